// Round 1
// baseline (633.724 us; speedup 1.0000x reference)
//
#include <hip/hip_runtime.h>
#include <math.h>

#define N_TOK 16384
#define DM    2048
#define NE    64
#define TOPK  4
#define TPW   8   // tokens per wave

#define OFF_TI  0
#define OFF_TS  (N_TOK * TOPK)
#define OFF_SC  (2 * N_TOK * TOPK)
#define OFF_AUX (2 * N_TOK * TOPK + N_TOK * NE)

// One wave (64 threads) per block; each wave handles TPW tokens.
// lane = expert index. E loads: coalesced VMEM dwords. u loads: wave-uniform
// addresses -> scalar (SMEM) pipe, keeping VMEM for E only.
__global__ __launch_bounds__(64) void router_main(
    const float* __restrict__ u, const float* __restrict__ E,
    const float* __restrict__ bias, float* __restrict__ out,
    float* __restrict__ ws)
{
  const int lane = threadIdx.x & 63;
  const long tb  = (long)blockIdx.x * TPW;   // first token of this wave

  float acc[TPW];
#pragma unroll
  for (int t = 0; t < TPW; ++t) acc[t] = 0.f;

  const float be = bias[lane];

  for (int d0 = 0; d0 < DM; d0 += 8) {
    float ev[8];
#pragma unroll
    for (int i = 0; i < 8; ++i) ev[i] = E[(size_t)(d0 + i) * NE + lane];
#pragma unroll
    for (int t = 0; t < TPW; ++t) {
      const float* __restrict__ ur = u + (size_t)(tb + t) * DM + d0;
      // 2-level accumulation: chunk partial then add (reduces rounding error
      // ~3x vs a single chained fma, protecting top-k index agreement).
      float c = ur[0] * ev[0];
#pragma unroll
      for (int i = 1; i < 8; ++i) c = fmaf(ur[i], ev[i], c);
      acc[t] += c;
    }
  }

  float asum = 0.f;
#pragma unroll
  for (int t = 0; t < TPW; ++t) {
    float x = acc[t] + be;

    // wave softmax across 64 experts (one per lane)
    float m = x;
#pragma unroll
    for (int off = 32; off > 0; off >>= 1) m = fmaxf(m, __shfl_xor(m, off));
    float p = expf(x - m);
    float s = p;
#pragma unroll
    for (int off = 32; off > 0; off >>= 1) s += __shfl_xor(s, off);
    float sc = p / s;

    out[OFF_SC + (size_t)(tb + t) * NE + lane] = sc;
    asum += sc;

    // top-4: 4 sequential wave arg-max reductions.
    // tie-break: larger value wins; equal value -> smaller index (lax.top_k).
    float v = sc;
#pragma unroll
    for (int k = 0; k < TOPK; ++k) {
      float bv = v;
      int   bi = lane;
#pragma unroll
      for (int off = 32; off > 0; off >>= 1) {
        float ov = __shfl_xor(bv, off);
        int   oi = __shfl_xor(bi, off);
        if (ov > bv || (ov == bv && oi < bi)) { bv = ov; bi = oi; }
      }
      if (lane == k) {
        out[OFF_TI + (size_t)(tb + t) * TOPK + k] = (float)bi;  // index as f32
        out[OFF_TS + (size_t)(tb + t) * TOPK + k] = bv;
      }
      if (lane == bi) v = -INFINITY;  // knock out winner
    }
  }

  // per-expert partial sums for aux loss (lane == expert)
  atomicAdd(&ws[lane], asum);
}

__global__ void router_aux(const float* __restrict__ ws, float* __restrict__ out)
{
  const int lane = threadIdx.x & 63;
  float m = ws[lane] * (1.0f / N_TOK);
  float v = m * m;
#pragma unroll
  for (int off = 32; off > 0; off >>= 1) v += __shfl_xor(v, off);
  if (lane == 0) out[OFF_AUX] = v * (float)NE;
}

extern "C" void kernel_launch(void* const* d_in, const int* in_sizes, int n_in,
                              void* d_out, int out_size, void* d_ws, size_t ws_size,
                              hipStream_t stream) {
  const float* u    = (const float*)d_in[0];
  const float* E    = (const float*)d_in[1];
  const float* bias = (const float*)d_in[2];
  float* out = (float*)d_out;
  float* ws  = (float*)d_ws;

  hipMemsetAsync(ws, 0, NE * sizeof(float), stream);
  router_main<<<N_TOK / TPW, 64, 0, stream>>>(u, E, bias, out, ws);
  router_aux<<<1, 64, 0, stream>>>(ws, out);
}

// Round 2
// 612.067 us; speedup vs baseline: 1.0354x; 1.0354x over previous
//
#include <hip/hip_runtime.h>
#include <math.h>

#define N_TOK 16384
#define DM    2048
#define NE    64
#define TOPK  4

#define OFF_TI  0
#define OFF_TS  (N_TOK * TOPK)
#define OFF_SC  (2 * N_TOK * TOPK)
#define OFF_AUX (2 * N_TOK * TOPK + N_TOK * NE)

#define NWAVE 16              // waves per block = split-K ways
#define KC    (DM / NWAVE)    // 128 dims per wave
#define DC    16              // dims per staging chunk
#define NCH   (KC / DC)       // 8 chunks per wave

// Block = 1024 threads = 16 waves, 64 tokens/block (lane = token).
// Each wave accumulates a 128-dim K-slice of all 64 experts for the block's
// 64 tokens: E rows are wave-uniform -> scalar loads (SGPR operand to fmac);
// u is staged coalesced into per-wave private LDS (no barriers in main loop).
// 256 blocks = 1 block/CU, 16 waves/CU (4/SIMD) to hide HBM + scalar latency.
__global__ __launch_bounds__(1024, 4) void router_main(
    const float* __restrict__ u, const float* __restrict__ E,
    const float* __restrict__ bias, float* __restrict__ out,
    float* __restrict__ ws)
{
  __shared__ float smem[NWAVE * DC * 64];   // 64 KB; reused as fin[64][65] after
  const int lane = threadIdx.x & 63;
  const int wid  = __builtin_amdgcn_readfirstlane(threadIdx.x >> 6); // wave-uniform!
  const int tok0 = blockIdx.x * 64;
  const int k0   = wid * KC;
  float* sm = smem + wid * (DC * 64);       // this wave's private staging buffer

  // staging assignment: lane covers 4 float4 per chunk; 4 consecutive lanes
  // cover one full 64B token-row segment -> perfect line utilization.
  const int stok = lane >> 2;          // token sub-index (+ j*16)
  const int sd4  = (lane & 3) * 4;     // dim offset of this lane's float4

  const float* ubase = u + (size_t)tok0 * DM;
  float4 pf[4];

  auto load_chunk = [&](int d0) {
#pragma unroll
    for (int j = 0; j < 4; ++j) {
      const float* p = ubase + (size_t)(j * 16 + stok) * DM + d0 + sd4;
      pf[j] = *(const float4*)p;
    }
  };
  // LDS layout (transposed): sm[d][tok], stride 64 -> compute reads
  // sm[kk*64+lane]: bank = lane%32, 2-way = free.
  auto store_chunk = [&]() {
#pragma unroll
    for (int j = 0; j < 4; ++j) {
      const int tok = j * 16 + stok;
      sm[(sd4 + 0) * 64 + tok] = pf[j].x;
      sm[(sd4 + 1) * 64 + tok] = pf[j].y;
      sm[(sd4 + 2) * 64 + tok] = pf[j].z;
      sm[(sd4 + 3) * 64 + tok] = pf[j].w;
    }
  };

  float acc[NE];
#pragma unroll
  for (int e = 0; e < NE; ++e) acc[e] = 0.f;

  load_chunk(k0);
  store_chunk();
  for (int c = 0; c < NCH; ++c) {
    const int d0 = k0 + c * DC;
    if (c + 1 < NCH) load_chunk(d0 + DC);   // prefetch overlaps compute below
#pragma unroll
    for (int kk = 0; kk < DC; ++kk) {
      const float uv = sm[kk * 64 + lane];                  // ds_read_b32
      const float* __restrict__ er = E + (size_t)(d0 + kk) * NE; // wave-uniform
#pragma unroll
      for (int e = 0; e < NE; ++e)
        acc[e] = fmaf(er[e], uv, acc[e]);   // v_fmac_f32 acc, sgpr, vgpr
    }
    if (c + 1 < NCH) store_chunk();  // same-wave DS in-order: safe single buffer
  }

  // ---- cross-wave split-K reduction into fin[64 tok][65] (padded) ----
  __syncthreads();
  float* fin = smem;
  for (int i = threadIdx.x; i < 64 * 65; i += 1024) fin[i] = 0.f;
  __syncthreads();
#pragma unroll
  for (int e = 0; e < NE; ++e)
    atomicAdd(&fin[lane * 65 + e], acc[e]);   // lane=token row; banks distinct
  __syncthreads();

  // ---- fused epilogue: wave w -> tokens w*4..w*4+3, lane = expert ----
  const float be = bias[lane];
  float asum = 0.f;
#pragma unroll
  for (int tt = 0; tt < 4; ++tt) {
    const int t = wid * 4 + tt;
    float x = fin[t * 65 + lane] + be;

    float m = x;
#pragma unroll
    for (int off = 32; off > 0; off >>= 1) m = fmaxf(m, __shfl_xor(m, off));
    float p = expf(x - m);
    float s = p;
#pragma unroll
    for (int off = 32; off > 0; off >>= 1) s += __shfl_xor(s, off);
    float sc = p / s;

    out[OFF_SC + (size_t)(tok0 + t) * NE + lane] = sc;
    asum += sc;

    // top-4, tie-break smaller index (matches lax.top_k)
    float v = sc;
#pragma unroll
    for (int k = 0; k < TOPK; ++k) {
      float bv = v;
      int   bi = lane;
#pragma unroll
      for (int off = 32; off > 0; off >>= 1) {
        float ov = __shfl_xor(bv, off);
        int   oi = __shfl_xor(bi, off);
        if (ov > bv || (ov == bv && oi < bi)) { bv = ov; bi = oi; }
      }
      if (lane == k) {
        out[OFF_TI + (size_t)(tok0 + t) * TOPK + k] = (float)bi;
        out[OFF_TS + (size_t)(tok0 + t) * TOPK + k] = bv;
      }
      if (lane == bi) v = -INFINITY;
    }
  }
  atomicAdd(&ws[lane], asum);   // per-expert partial for aux loss
}

__global__ void router_aux(const float* __restrict__ ws, float* __restrict__ out)
{
  const int lane = threadIdx.x & 63;
  float m = ws[lane] * (1.0f / N_TOK);
  float v = m * m;
#pragma unroll
  for (int off = 32; off > 0; off >>= 1) v += __shfl_xor(v, off);
  if (lane == 0) out[OFF_AUX] = v * (float)NE;
}

extern "C" void kernel_launch(void* const* d_in, const int* in_sizes, int n_in,
                              void* d_out, int out_size, void* d_ws, size_t ws_size,
                              hipStream_t stream) {
  const float* u    = (const float*)d_in[0];
  const float* E    = (const float*)d_in[1];
  const float* bias = (const float*)d_in[2];
  float* out = (float*)d_out;
  float* ws  = (float*)d_ws;

  hipMemsetAsync(ws, 0, NE * sizeof(float), stream);
  router_main<<<N_TOK / 64, 1024, 0, stream>>>(u, E, bias, out, ws);
  router_aux<<<1, 64, 0, stream>>>(ws, out);
}

// Round 3
// 445.450 us; speedup vs baseline: 1.4227x; 1.3740x over previous
//
#include <hip/hip_runtime.h>
#include <math.h>

#define N_TOK 16384
#define DM    2048
#define NE    64
#define TOPK  4

#define OFF_TI  0
#define OFF_TS  (N_TOK * TOPK)
#define OFF_SC  (2 * N_TOK * TOPK)
#define OFF_AUX (2 * N_TOK * TOPK + N_TOK * NE)

#define TPB   64              // tokens per block
#define DC    32              // dims per chunk per K-half
#define NCH   (1024 / DC)     // 32 chunks
#define LSTR  68              // LDS row stride (dwords): 64 dims + 4 pad
                              // 68 ≡ 4 (mod 32): both b128 write (4(tok+dseg))
                              // and b128 read (4*lane+K) hit minimal 8 phases.

// Block: 1024 threads = 16 waves, 64 tokens. lane = token.
// wave (eg, kh): experts eg*8..+8, dims kh*1024..+1024 -> acc[8]/lane (no spill).
// u: coalesced float4 -> LDS [tok][d] (stride 68), 3-deep prefetch, 1 barrier/chunk.
// E: wave-uniform rows -> s_load (scalar pipe, L2-hot 512KB) feeding v_fmac src0.
__global__ __launch_bounds__(1024, 4) void router_main(
    const float* __restrict__ u, const float* __restrict__ E,
    const float* __restrict__ bias, float* __restrict__ out,
    float* __restrict__ ws)
{
  __shared__ float smem[2 * TPB * LSTR];   // 34.8 KB; aliased as fin[64][65] after

  const int tid  = threadIdx.x;
  const int lane = tid & 63;
  const int wid  = __builtin_amdgcn_readfirstlane(tid >> 6);
  const int eg   = wid & 7;     // expert group
  const int kh   = wid >> 3;    // K half
  const int tok0 = blockIdx.x * TPB;

  // ---- staging assignment: thread -> (token, 16B dim-segment) ----
  const int stok  = tid >> 4;        // 0..63
  const int sdseg = tid & 15;        // 0..7 -> kh0 dims, 8..15 -> kh1 dims
  const int skh   = sdseg >> 3;
  const int sdsub = (sdseg & 7) * 4; // dim offset within 32-dim half-chunk
  const float* sgbase = u + (size_t)(tok0 + stok) * DM + skh * 1024 + sdsub;
  float* swp = smem + stok * LSTR + sdseg * 4;   // + buf*TPB*LSTR

  float acc[8];
#pragma unroll
  for (int j = 0; j < 8; ++j) acc[j] = 0.f;

  const float* Ebase = E + eg * 8;   // E[d][e], row stride NE

  float4 pf[3];
  pf[0] = *(const float4*)(sgbase + 0 * DC);
  pf[1] = *(const float4*)(sgbase + 1 * DC);
  pf[2] = *(const float4*)(sgbase + 2 * DC);
  *(float4*)(swp + 0) = pf[0];       // chunk 0 -> buf 0
  __syncthreads();

  for (int c = 0; c < NCH; ++c) {
    // stage chunk c+1 into the other buffer (its readers sync'd last iter)
    if (c + 1 < NCH)
      *(float4*)(swp + ((c + 1) & 1) * (TPB * LSTR)) = pf[(c + 1) % 3];
    // refill the consumed prefetch slot with chunk c+3
    if (c + 3 < NCH)
      pf[c % 3] = *(const float4*)(sgbase + (c + 3) * DC);

    // ---- compute chunk c ----
    const float* sb = smem + (c & 1) * (TPB * LSTR) + lane * LSTR + kh * DC;
    const int dg0 = kh * 1024 + c * DC;   // global dim base (wave-uniform)
#pragma unroll
    for (int s = 0; s < 8; ++s) {         // 4 dims per sub-step
      float4 uf = *(const float4*)(sb + s * 4);   // ds_read_b128, 8-phase min
#pragma unroll
      for (int dd = 0; dd < 4; ++dd) {
        const float* __restrict__ er = Ebase + (size_t)(dg0 + s * 4 + dd) * NE;
        const float uv = (&uf.x)[dd];
#pragma unroll
        for (int j = 0; j < 8; ++j)
          acc[j] = fmaf(er[j], uv, acc[j]);   // v_fmac acc, sgpr(E), vgpr(u)
      }
    }
    __syncthreads();
  }

  // ---- cross-wave K-half reduction into fin[64 tok][65] (aliases smem) ----
  float* fin = smem;
  if (kh == 0) {
#pragma unroll
    for (int j = 0; j < 8; ++j) fin[lane * 65 + eg * 8 + j] = acc[j];
  }
  __syncthreads();
  if (kh == 1) {
#pragma unroll
    for (int j = 0; j < 8; ++j) fin[lane * 65 + eg * 8 + j] += acc[j];
  }
  __syncthreads();

  // ---- epilogue: wave w -> tokens w*4..+3, lane = expert (round-2 verified) ----
  const float be = bias[lane];
  float asum = 0.f;
#pragma unroll
  for (int tt = 0; tt < 4; ++tt) {
    const int t = wid * 4 + tt;
    float x = fin[t * 65 + lane] + be;

    float m = x;
#pragma unroll
    for (int off = 32; off > 0; off >>= 1) m = fmaxf(m, __shfl_xor(m, off));
    float p = expf(x - m);
    float s = p;
#pragma unroll
    for (int off = 32; off > 0; off >>= 1) s += __shfl_xor(s, off);
    float sc = p / s;

    out[OFF_SC + (size_t)(tok0 + t) * NE + lane] = sc;
    asum += sc;

    float v = sc;
#pragma unroll
    for (int k = 0; k < TOPK; ++k) {
      float bv = v;
      int   bi = lane;
#pragma unroll
      for (int off = 32; off > 0; off >>= 1) {
        float ov = __shfl_xor(bv, off);
        int   oi = __shfl_xor(bi, off);
        if (ov > bv || (ov == bv && oi < bi)) { bv = ov; bi = oi; }
      }
      if (lane == k) {
        out[OFF_TI + (size_t)(tok0 + t) * TOPK + k] = (float)bi;
        out[OFF_TS + (size_t)(tok0 + t) * TOPK + k] = bv;
      }
      if (lane == bi) v = -INFINITY;
    }
  }
  atomicAdd(&ws[lane], asum);   // per-expert partial for aux loss
}

__global__ void router_aux(const float* __restrict__ ws, float* __restrict__ out)
{
  const int lane = threadIdx.x & 63;
  float m = ws[lane] * (1.0f / N_TOK);
  float v = m * m;
#pragma unroll
  for (int off = 32; off > 0; off >>= 1) v += __shfl_xor(v, off);
  if (lane == 0) out[OFF_AUX] = v * (float)NE;
}

extern "C" void kernel_launch(void* const* d_in, const int* in_sizes, int n_in,
                              void* d_out, int out_size, void* d_ws, size_t ws_size,
                              hipStream_t stream) {
  const float* u    = (const float*)d_in[0];
  const float* E    = (const float*)d_in[1];
  const float* bias = (const float*)d_in[2];
  float* out = (float*)d_out;
  float* ws  = (float*)d_ws;

  hipMemsetAsync(ws, 0, NE * sizeof(float), stream);
  router_main<<<N_TOK / TPB, 1024, 0, stream>>>(u, E, bias, out, ws);
  router_aux<<<1, 64, 0, stream>>>(ws, out);
}